// Round 5
// baseline (4933.969 us; speedup 1.0000x reference)
//
#include <hip/hip_runtime.h>

// EP free-phase relaxation — fp16 MFMA, 2-term activation split.
// B=256, D=4096, N=30, DT=0.5.
//   n0 = clip(0.5*c0 + 0.5*(r1@W0^T + b0))
//   n1 = clip(0.5*c1 + 0.5*(r2@W2^T + r0@W1^T + b2))   (split-K partials p0+p1)
//   n2 = clip(0.5*c2 + 0.5*(top + r1@W3^T))            top = r3@W4^T + b4
// Numerics: W fp16; activations split hi+lo fp16 into one fp32 MFMA accumulator,
// MFMA K-order bitwise-identical to R4 (absmax 7.8e-3).
//
// R5 structure change: W DIRECT-TO-REGISTER (no LDS staging for W).
//   R4 post-mortem: no pipe >33% busy; limiter = phase-locked per-wave chain
//   {barrier, 8 ds_read, lgkm, 16 MFMA}. W frags have ZERO intra-block reuse ->
//   LDS staging of W was pure overhead (62% of LDS traffic + barrier coupling).
//  - BK=64, nk=64. Per iter/wave: 8 global_load_dwordx4 -> wfN regs (tile kk+1,
//    compiler-tracked waits), 2 gl_lds A (tile kk+2, 3 x 8KB buffers, counted
//    vmcnt), 8 ds_read_b128 A, 32 MFMA. wfA/wfB static double-buffer (loop
//    unrolled x2 to avoid dynamic-indexed reg arrays).
//  - vmcnt group math: per iter issues W:8 then A:2 (10/group). At iter kk, ops
//    newer than A(kk)'s group = group(kk-1) = 10 (8 if kk=nk-1) -> wait
//    vmcnt(10)/vmcnt(8). Invariant to intra-group reorder; compiler's own
//    tracked waits cover the W-reg path independently.
//  - A LDS: [32 rows][128B] hi @0, lo @4096; chunk swizzle c^=(row&7) on global
//    src + ds_read offset (2-way bank overlap = free).
//  - Grid 512 uniform (z0 | z1a->p0 | z1b->p1 | z2), finish_l1 merges layer 1.

typedef unsigned short u16;
typedef __attribute__((ext_vector_type(8))) _Float16 f16x8;
typedef __attribute__((ext_vector_type(4))) float f32x4;

constexpr int Bb = 256, Dd = 4096, NSTEPS = 30;
constexpr long BD = (long)Bb * Dd;   // 1,048,576
constexpr long DD = (long)Dd * Dd;   // 16,777,216
constexpr int BM = 32;
constexpr int NBUF = 3;
constexpr int BUFB = 8192;           // per-buffer: AsH 4K | AsL 4K

__device__ inline u16 f2h(float f) { union { _Float16 h; u16 u; } v; v.h = (_Float16)f; return v.u; }
__device__ inline float h2f(u16 b) { union { u16 u; _Float16 h; } v; v.u = b; return (float)v.h; }

__device__ inline void gl_lds16(const u16* g, void* l) {
    __builtin_amdgcn_global_load_lds(
        (const __attribute__((address_space(1))) void*)g,
        (__attribute__((address_space(3))) void*)l, 16, 0, 0);
}

__global__ __launch_bounds__(256)
void convert_w(const float* __restrict__ src, u16* __restrict__ dst, long n) {
    long i = (long)blockIdx.x * blockDim.x + threadIdx.x;
    const long stride = (long)gridDim.x * blockDim.x;
    for (long v = i; v < (n >> 2); v += stride) {
        float4 x = ((const float4*)src)[v];
        ushort4 o; o.x = f2h(x.x); o.y = f2h(x.y); o.z = f2h(x.z); o.w = f2h(x.w);
        ((ushort4*)dst)[v] = o;
    }
}

__global__ __launch_bounds__(256)
void convert_s(const float* __restrict__ src, u16* __restrict__ hi, u16* __restrict__ lo, long n) {
    long i = (long)blockIdx.x * blockDim.x + threadIdx.x;
    const long stride = (long)gridDim.x * blockDim.x;
    for (long v = i; v < (n >> 2); v += stride) {
        float4 x = ((const float4*)src)[v];
        float a[4] = {x.x, x.y, x.z, x.w};
        ushort4 oh, ol;
        u16* ph = (u16*)&oh; u16* pl = (u16*)&ol;
        #pragma unroll
        for (int j = 0; j < 4; ++j) {
            float c = fminf(fmaxf(a[j], 0.f), 1.f);
            u16 hb = f2h(c);
            ph[j] = hb;
            pl[j] = f2h(c - h2f(hb));
        }
        ((ushort4*)hi)[v] = oh;
        ((ushort4*)lo)[v] = ol;
    }
}

// FULL=false: outF[idx] = acc (+bias)           (top and split-K partials)
// FULL=true : full step epilogue (prev merge, clip, hi/lo split)
template<bool FULL>
__device__ inline void run_gemm(const u16* aH, const u16* aL, const u16* W,
                                const int m0, const int n0, char* smem,
                                const float* bias, const float* add,
                                const float* pF, const u16* pH, const u16* pL,
                                float* outF, u16* oH, u16* oL, const long zOff)
{
    const int lane = threadIdx.x & 63, wv = threadIdx.x >> 6;
    const int r16 = lane & 15, q = lane >> 4;
    f32x4 acc[2][4] = {};
    constexpr int nk = 64;           // 4096 / BK, BK = 64

    // Per-lane W row pointers: frag j row = n0+64wv+16j+(lane&15); lane chunk q*8
    // elems. Load pattern per instr: 16 rows x 64 contiguous B -> line-coalesced.
    const u16* wp[4];
    #pragma unroll
    for (int j = 0; j < 4; ++j)
        wp[j] = W + (size_t)(n0 + 64 * wv + 16 * j + r16) * Dd + q * 8;

    // A staging: wave wv stages rows [8wv,8wv+8) of hi and of lo (2 gl_lds of 1KB).
    // LDS row r (128B) slot c holds global chunk c^(r&7); for the linear gl_lds
    // dest (lane*16), r&7 == lane>>3, so src chunk = (lane&7)^(lane>>3).
    const int arow = 8 * wv + (lane >> 3);
    const int aswz = ((lane & 7) ^ (lane >> 3)) * 8;
    const u16* aSrcH = aH + (size_t)(m0 + arow) * Dd + aswz;
    const u16* aSrcL = aL + (size_t)(m0 + arow) * Dd + aswz;

    // ds_read offsets: row = 16i+r16, global chunk g = 4h+q -> slot g^(r16&7).
    int aoff[2][2];
    #pragma unroll
    for (int i = 0; i < 2; ++i)
        #pragma unroll
        for (int h = 0; h < 2; ++h)
            aoff[i][h] = (16 * i + r16) * 128 + (((4 * h + q) ^ (r16 & 7)) << 4);

    int ib = 0;
    f16x8 wfA[4][2], wfB[4][2];

    auto stageA = [&](int kt, char* buf) {
        gl_lds16(aSrcH + 64 * kt, buf + (wv << 10));
        gl_lds16(aSrcL + 64 * kt, buf + 4096 + (wv << 10));
    };

    auto body = [&](int kk, f16x8 (&wfC)[4][2], f16x8 (&wfN)[4][2]) {
        // A(kk)'s 2 gl_lds retired when outstanding <= group(kk-1) size.
        if (kk <= nk - 2) asm volatile("s_waitcnt vmcnt(10)" ::: "memory");
        else              asm volatile("s_waitcnt vmcnt(8)"  ::: "memory");
        __builtin_amdgcn_s_barrier();
        asm volatile("" ::: "memory");

        if (kk + 1 < nk) {                       // W(kk+1) -> wfN (8 loads)
            const int ko = 64 * (kk + 1);
            #pragma unroll
            for (int j = 0; j < 4; ++j)
                #pragma unroll
                for (int h = 0; h < 2; ++h)
                    wfN[j][h] = *(const f16x8*)(wp[j] + ko + 32 * h);
        }
        if (kk + 2 < nk) {                       // A(kk+2) -> LDS (2 gl_lds)
            int ib2 = ib + 2; if (ib2 >= NBUF) ib2 -= NBUF;
            stageA(kk + 2, smem + ib2 * BUFB);
        }

        const char* buf = smem + ib * BUFB;
        ++ib; if (ib == NBUF) ib = 0;

        __builtin_amdgcn_s_setprio(1);
        #pragma unroll
        for (int h = 0; h < 2; ++h) {
            f16x8 ah[2], al[2];
            #pragma unroll
            for (int i = 0; i < 2; ++i) {
                ah[i] = *(const f16x8*)(buf + aoff[i][h]);
                al[i] = *(const f16x8*)(buf + 4096 + aoff[i][h]);
            }
            #pragma unroll
            for (int j = 0; j < 4; ++j)
                #pragma unroll
                for (int i = 0; i < 2; ++i) {
                    acc[i][j] = __builtin_amdgcn_mfma_f32_16x16x32_f16(ah[i], wfC[j][h], acc[i][j], 0, 0, 0);
                    acc[i][j] = __builtin_amdgcn_mfma_f32_16x16x32_f16(al[i], wfC[j][h], acc[i][j], 0, 0, 0);
                }
        }
        __builtin_amdgcn_s_setprio(0);
    };

    // Prologue: A(0), A(1), W(0). (12 vmem ops; A(0) has 10 newer -> vmcnt(10) at kk=0.)
    stageA(0, smem);
    stageA(1, smem + BUFB);
    #pragma unroll
    for (int j = 0; j < 4; ++j)
        #pragma unroll
        for (int h = 0; h < 2; ++h)
            wfA[j][h] = *(const f16x8*)(wp[j] + 32 * h);

    for (int kk2 = 0; kk2 < nk; kk2 += 2) {      // static wfA/wfB role swap
        body(kk2,     wfA, wfB);
        body(kk2 + 1, wfB, wfA);
    }

    // Epilogue. C/D layout: row m = (lane>>4)*4 + reg, col n = lane&15.
    #pragma unroll
    for (int j = 0; j < 4; ++j) {
        const int n = n0 + 64 * wv + 16 * j + r16;
        #pragma unroll
        for (int i = 0; i < 2; ++i) {
            #pragma unroll
            for (int r = 0; r < 4; ++r) {
                const int m = m0 + 16 * i + q * 4 + r;
                const size_t idx = (size_t)m * Dd + n;
                float e = acc[i][j][r];
                if (!FULL) {
                    outF[idx] = bias ? e + bias[n] : e;
                } else {
                    if (bias) e += bias[n];
                    if (add)  e += add[idx];
                    const float p = pF ? pF[zOff + idx] : (h2f(pH[zOff + idx]) + h2f(pL[zOff + idx]));
                    float v = 0.5f * p + 0.5f * e;
                    v = fminf(fmaxf(v, 0.f), 1.f);
                    const u16 hb = f2h(v);
                    oH[zOff + idx] = hb;
                    oL[zOff + idx] = f2h(v - h2f(hb));
                    if (outF) outF[zOff + idx] = v;
                }
            }
        }
    }
}

// MODE 0: top = rho(s3)@W4^T + b4, grid 128 (W4h/b4 in W0h/b0 slots).
// MODE 1: fused step, grid 512 uniform:
//   [0,128)   z0 : full epi, A=r1, W0, b0, zOff 0
//   [128,256) z1a: partial p0 = r2@W2^T + b2
//   [256,384) z1b: partial p1 = r0@W1^T
//   [384,512) z2 : full epi, A=r1, W3, add=top, zOff 2BD
template<int MODE>
__global__ __launch_bounds__(256, 2)
void step_mfma(const u16* __restrict__ sH, const u16* __restrict__ sL,
               const u16* __restrict__ W0h, const u16* __restrict__ W1h,
               const u16* __restrict__ W2h, const u16* __restrict__ W3h,
               const float* __restrict__ b0, const float* __restrict__ b2,
               const float* __restrict__ top,
               const float* __restrict__ pF,
               const u16* __restrict__ pH, const u16* __restrict__ pL,
               float* __restrict__ outF,
               u16* __restrict__ oH, u16* __restrict__ oL,
               float* __restrict__ p0, float* __restrict__ p1)
{
    __shared__ __align__(16) char smem[NBUF * BUFB];   // 24 KB
    const int id = blockIdx.x;

    if (MODE == 0) {
        const int mt = id >> 4, nt = id & 15;
        run_gemm<false>(sH, sL, W0h, mt * BM, nt * 256, smem, b0, nullptr,
                        nullptr, nullptr, nullptr, outF, nullptr, nullptr, 0);
    } else {
        const int t = id & 127, mt = t >> 4, nt = t & 15;
        const int m0 = mt * BM, n0 = nt * 256;
        if (id < 128) {              // z0
            run_gemm<true>(sH + BD, sL + BD, W0h, m0, n0, smem, b0, nullptr,
                           pF, pH, pL, outF, oH, oL, 0);
        } else if (id < 256) {       // z1a -> p0
            run_gemm<false>(sH + 2 * BD, sL + 2 * BD, W2h, m0, n0, smem, b2, nullptr,
                            nullptr, nullptr, nullptr, p0, nullptr, nullptr, 0);
        } else if (id < 384) {       // z1b -> p1
            run_gemm<false>(sH, sL, W1h, m0, n0, smem, nullptr, nullptr,
                            nullptr, nullptr, nullptr, p1, nullptr, nullptr, 0);
        } else {                     // z2
            run_gemm<true>(sH + BD, sL + BD, W3h, m0, n0, smem, nullptr, top,
                           pF, pH, pL, outF, oH, oL, 2 * BD);
        }
    }
}

// n1 = clip(0.5*prev1 + 0.5*(p0+p1)); hi/lo split; optional fp32 out (last step).
__global__ __launch_bounds__(256)
void finish_l1(const float* __restrict__ p0, const float* __restrict__ p1,
               const float* __restrict__ pF,
               const u16* __restrict__ pH, const u16* __restrict__ pL,
               float* __restrict__ outF, u16* __restrict__ oH, u16* __restrict__ oL)
{
    const long v = (long)blockIdx.x * blockDim.x + threadIdx.x;   // float4 index, BD/4 total
    float4 a = ((const float4*)p0)[v];
    float4 b = ((const float4*)p1)[v];
    float e[4] = {a.x + b.x, a.y + b.y, a.z + b.z, a.w + b.w};
    float p[4];
    if (pF) {
        float4 pv = ((const float4*)(pF + BD))[v];
        p[0] = pv.x; p[1] = pv.y; p[2] = pv.z; p[3] = pv.w;
    } else {
        ushort4 hv = ((const ushort4*)(pH + BD))[v];
        ushort4 lv = ((const ushort4*)(pL + BD))[v];
        p[0] = h2f(hv.x) + h2f(lv.x); p[1] = h2f(hv.y) + h2f(lv.y);
        p[2] = h2f(hv.z) + h2f(lv.z); p[3] = h2f(hv.w) + h2f(lv.w);
    }
    ushort4 oh, ol; u16* ph = (u16*)&oh; u16* pl = (u16*)&ol;
    float4 ov;
    float* po = (float*)&ov;
    #pragma unroll
    for (int j = 0; j < 4; ++j) {
        float x = 0.5f * p[j] + 0.5f * e[j];
        x = fminf(fmaxf(x, 0.f), 1.f);
        const u16 hb = f2h(x);
        ph[j] = hb;
        pl[j] = f2h(x - h2f(hb));
        po[j] = x;
    }
    ((ushort4*)(oH + BD))[v] = oh;
    ((ushort4*)(oL + BD))[v] = ol;
    if (outF) ((float4*)(outF + BD))[v] = ov;
}

extern "C" void kernel_launch(void* const* d_in, const int* in_sizes, int n_in,
                              void* d_out, int out_size, void* d_ws, size_t ws_size,
                              hipStream_t stream)
{
    const float* s0 = (const float*)d_in[0];
    const float* s1 = (const float*)d_in[1];
    const float* s2 = (const float*)d_in[2];
    const float* s3 = (const float*)d_in[3];
    const float* W0 = (const float*)d_in[4];
    const float* b0 = (const float*)d_in[5];
    const float* W1 = (const float*)d_in[6];
    const float* W2 = (const float*)d_in[7];
    const float* b2 = (const float*)d_in[8];
    const float* W3 = (const float*)d_in[9];
    const float* W4 = (const float*)d_in[10];
    const float* b4 = (const float*)d_in[11];

    float* top = (float*)d_ws;                      // BD fp32 = 4 MB
    u16* u   = (u16*)(top + BD);
    u16* W0h = u;            u16* W1h = u + DD;     u16* W2h = u + 2 * DD;
    u16* W3h = u + 3 * DD;   u16* W4h = u + 4 * DD; // 160 MB total for weights
    u16* sHa = u + 5 * DD;      // 3*BD hi ping
    u16* sLa = sHa + 3 * BD;    // 3*BD lo ping
    u16* sHb = sLa + 3 * BD;    // 3*BD hi pong
    u16* sLb = sHb + 3 * BD;    // 3*BD lo pong
    u16* s3h = sLb + 3 * BD;
    u16* s3l = s3h + BD;
    // Split-K partials ALIAS the W4h region (32 MB): W4h is consumed only by the
    // MODE0 "top" kernel, which is stream-ordered before every step_mfma<1>.
    // Total workspace stays at the verified 192 MB.
    float* p0 = (float*)W4h;          // BD fp32 (4 MB)
    float* p1 = p0 + BD;              // BD fp32 (4 MB)

    float* out = (float*)d_out;
    const dim3 blk(256);
    const dim3 cgrid(512);

    convert_w<<<cgrid, blk, 0, stream>>>(W0, W0h, DD);
    convert_w<<<cgrid, blk, 0, stream>>>(W1, W1h, DD);
    convert_w<<<cgrid, blk, 0, stream>>>(W2, W2h, DD);
    convert_w<<<cgrid, blk, 0, stream>>>(W3, W3h, DD);
    convert_w<<<cgrid, blk, 0, stream>>>(W4, W4h, DD);
    convert_s<<<cgrid, blk, 0, stream>>>(s3, s3h, s3l, BD);
    convert_s<<<cgrid, blk, 0, stream>>>(s0, sHa,          sLa,          BD);
    convert_s<<<cgrid, blk, 0, stream>>>(s1, sHa + BD,     sLa + BD,     BD);
    convert_s<<<cgrid, blk, 0, stream>>>(s2, sHa + 2 * BD, sLa + 2 * BD, BD);

    // top = rho(s3) @ W4^T + b4   (last use of W4h; p0/p1 overwrite it afterwards)
    step_mfma<0><<<dim3(128), blk, 0, stream>>>(
        s3h, s3l, W4h, nullptr, nullptr, nullptr,
        b4, nullptr, nullptr,
        nullptr, nullptr, nullptr,
        top, nullptr, nullptr, nullptr, nullptr);

    for (int t = 0; t < NSTEPS; ++t) {
        const u16* iH = (t & 1) ? sHb : sHa;
        const u16* iL = (t & 1) ? sLb : sLa;
        u16*       vH = (t & 1) ? sHa : sHb;
        u16*       vL = (t & 1) ? sLa : sLb;
        float* oF = (t == NSTEPS - 1) ? out : nullptr;
        const float* pF = nullptr;
        if (t == 0) {
            // prev must be the raw fp32 inputs; stage them contiguously in d_out
            hipMemcpyAsync(out,          s0, BD * sizeof(float), hipMemcpyDeviceToDevice, stream);
            hipMemcpyAsync(out + BD,     s1, BD * sizeof(float), hipMemcpyDeviceToDevice, stream);
            hipMemcpyAsync(out + 2 * BD, s2, BD * sizeof(float), hipMemcpyDeviceToDevice, stream);
            pF = out;
        }
        step_mfma<1><<<dim3(512), blk, 0, stream>>>(
            iH, iL, W0h, W1h, W2h, W3h, b0, b2, top,
            pF, iH, iL,
            oF, vH, vL, p0, p1);
        finish_l1<<<dim3(BD / 4 / 256), blk, 0, stream>>>(
            p0, p1, pF, iH, iL, oF, vH, vL);
    }
}